// Round 5
// baseline (68.155 us; speedup 1.0000x reference)
//
#include <hip/hip_runtime.h>

#define NIMG 8
#define NC 19
#define HW (512*1024)
#define BPI 64           // blocks per image
#define TPB 512
#define ITERS 8          // float2 chunks/thread: (HW/2)/(BPI*TPB) = 262144/32768
#define CPB (ITERS*TPB)  // float2 chunks per block = 4096 (32KB/plane contiguous)
#define OLD_CL 11
#define NWAVE (TPB/64)

typedef float    f32x2 __attribute__((ext_vector_type(2)));

// ---------------- main pass: per-pixel softmax^2 per-class sums + argmax hist ----------------
// Partials written TRANSPOSED: sPart[c][n][bl], hPart[c][n][bl]
__global__ __launch_bounds__(TPB, 4) void iw_main(const float* __restrict__ in,
                                                  float* __restrict__ sPart,
                                                  unsigned* __restrict__ hPart) {
    const int b   = blockIdx.x;        // 0 .. NIMG*BPI-1
    const int n   = b >> 6;            // image (BPI=64)
    const int bl  = b & (BPI - 1);
    const int tid = threadIdx.x;
    const float* img = in + (size_t)n * NC * HW;

    float    acc[NC];
    unsigned hc[5];                    // 19 counters x 8-bit fields (max 16 px/thread)
#pragma unroll
    for (int c = 0; c < NC; ++c) acc[c] = 0.f;
#pragma unroll
    for (int r = 0; r < 5; ++r) hc[r] = 0u;

    const float L2E = 1.4426950408889634f;

    for (int it = 0; it < ITERS; ++it) {
        // contiguous per-block mapping: block streams 32KB/plane sequentially
        const int    chunk = bl * CPB + it * TPB + tid;
        const size_t p     = (size_t)chunk * 2;

        float x0[NC], x1[NC];
#pragma unroll
        for (int c = 0; c < NC; ++c) {
            const f32x2 t = __builtin_nontemporal_load(
                reinterpret_cast<const f32x2*>(img + (size_t)c * HW + p));
            x0[c] = t[0]; x1[c] = t[1];
        }

#define PIXEL(X)                                                              \
        {                                                                     \
            float m = X[0];                                                   \
            _Pragma("unroll")                                                 \
            for (int c = 1; c < NC; ++c) m = fmaxf(m, X[c]);                  \
            int mi = NC - 1;                                                  \
            _Pragma("unroll")                                                 \
            for (int c = NC - 2; c >= 0; --c) mi = (X[c] == m) ? c : mi;      \
            {                                                                 \
                const unsigned inc = 1u << ((mi & 3) * 8);                    \
                const int r = mi >> 2;                                        \
                hc[0] += (r == 0) ? inc : 0u;                                 \
                hc[1] += (r == 1) ? inc : 0u;                                 \
                hc[2] += (r == 2) ? inc : 0u;                                 \
                hc[3] += (r == 3) ? inc : 0u;                                 \
                hc[4] += (r == 4) ? inc : 0u;                                 \
            }                                                                 \
            const float ml = m * L2E;                                         \
            float e[NC]; float d = 0.f;                                       \
            _Pragma("unroll")                                                 \
            for (int c = 0; c < NC; ++c) {                                    \
                e[c] = exp2f(fmaf(X[c], L2E, -ml));                           \
                d += e[c];                                                    \
            }                                                                 \
            const float inv  = __builtin_amdgcn_rcpf(d);                      \
            const float inv2 = inv * inv;                                     \
            _Pragma("unroll")                                                 \
            for (int c = 0; c < NC; ++c)                                      \
                acc[c] = fmaf(e[c] * e[c], inv2, acc[c]);                     \
        }

        PIXEL(x0); PIXEL(x1);
#undef PIXEL
    }

    // ---- unpack hist, wave (64-lane) butterfly reduce ----
    unsigned hu[NC];
#pragma unroll
    for (int c = 0; c < NC; ++c) hu[c] = (hc[c >> 2] >> ((c & 3) * 8)) & 0xFFu;

#pragma unroll
    for (int c = 0; c < NC; ++c) {
#pragma unroll
        for (int off = 32; off >= 1; off >>= 1) {
            acc[c] += __shfl_xor(acc[c], off, 64);
            hu[c]  += (unsigned)__shfl_xor((int)hu[c], off, 64);
        }
    }

    // ---- cross-wave combine via LDS (8 waves/block), deterministic ----
    __shared__ float    ls[NWAVE][NC];
    __shared__ unsigned lh[NWAVE][NC];
    const int wave = tid >> 6;
    const int lane = tid & 63;
    if (lane == 0) {
#pragma unroll
        for (int c = 0; c < NC; ++c) { ls[wave][c] = acc[c]; lh[wave][c] = hu[c]; }
    }
    __syncthreads();
    if (tid < NC) {
        float s = 0.f; unsigned h = 0u;
#pragma unroll
        for (int w = 0; w < NWAVE; ++w) { s += ls[w][tid]; h += lh[w][tid]; }
        // transposed: [c][n][bl]
        sPart[(size_t)tid * (NIMG * BPI) + n * BPI + bl] = s;
        hPart[(size_t)tid * (NIMG * BPI) + n * BPI + bl] = h;
    }
}

// ---------------- final reduce: coalesced wave-parallel partial reduce -> weight -> loss ----------------
__global__ __launch_bounds__(1024) void iw_final(const float* __restrict__ sPart,
                                                 const unsigned* __restrict__ hPart,
                                                 float* __restrict__ out) {
    __shared__ float    sRed[NIMG * NC];
    __shared__ unsigned hRed[NIMG * NC];
    __shared__ double contrib[NIMG * NC];
    __shared__ double histL[NIMG * NC];
    __shared__ double hsum[NIMG];

    const int t    = threadIdx.x;
    const int wv   = t >> 6;           // 16 waves
    const int lane = t & 63;

    // each wave handles pairs wv, wv+16, ... (10 slots cover 152 pairs); BPI=64 -> 1 f32/lane
#pragma unroll
    for (int i = 0; i < 10; ++i) {
        const int pair = wv + 16 * i;
        if (pair < NIMG * NC) {
            const size_t base = (size_t)pair * BPI + lane;
            float    s = sPart[base];
            unsigned h = hPart[base];
#pragma unroll
            for (int off = 32; off >= 1; off >>= 1) {
                s += __shfl_xor(s, off, 64);
                h += (unsigned)__shfl_xor((int)h, off, 64);
            }
            if (lane == 0) { sRed[pair] = s; hRed[pair] = h; }
        }
    }
    __syncthreads();

    // pair index is [c][n] linear; convert to canonical (n,c)
    if (t < NIMG * NC) {
        const int c = t / NIMG, n = t % NIMG;
        const int idx = n * NC + c;
        const unsigned h = hRed[t];
        histL[idx]   = (h == 0u) ? 1.0 : (double)h;
        contrib[idx] = (double)sRed[t];              // temporarily S
    }
    __syncthreads();
    if (t < NIMG) {
        double hs = 0.0;
        for (int c = 0; c < NC; ++c) hs += histL[t * NC + c];
        hsum[t] = hs;
    }
    __syncthreads();
    if (t < NIMG * NC) {
        const int n = t / NC, c = t % NC;
        const double w = (c < OLD_CL) ? 1.0 : pow(hsum[n] / histL[t], 0.2);
        contrib[t] = w * contrib[t];
    }
    __syncthreads();
    if (t == 0) {
        double tot = 0.0;
        for (int i = 0; i < NIMG * NC; ++i) tot += contrib[i];
        out[0] = (float)(-tot / (double)((size_t)NIMG * NC * HW));
    }
}

extern "C" void kernel_launch(void* const* d_in, const int* in_sizes, int n_in,
                              void* d_out, int out_size, void* d_ws, size_t ws_size,
                              hipStream_t stream) {
    const float* in = (const float*)d_in[0];
    float* out = (float*)d_out;

    float*    sPart = (float*)d_ws;
    unsigned* hPart = (unsigned*)((char*)d_ws + (size_t)NC * NIMG * BPI * sizeof(float));

    iw_main<<<dim3(NIMG * BPI), TPB, 0, stream>>>(in, sPart, hPart);
    iw_final<<<1, 1024, 0, stream>>>(sPart, hPart, out);
}